// Round 3
// baseline (329.118 us; speedup 1.0000x reference)
//
#include <hip/hip_runtime.h>

// SoftPhongNormalShader, two-phase (R7 = R4 structure + nt gathers):
//   Phase 1: per-face table, ONE 16-B row per face: 3 vertex normals packed
//            as 3x10-bit unorm codes per dword ({n0,n1,n2,0}). 1.6 MB ->
//            L2-resident; exactly ONE divergent 16-B load per fragment.
//   Phase 2: per-pixel shade + softmax blend (pixel-parallel, 1.20 lines/frag
//            -- the request-count minimum of the two structures).
//
// R6 post-mortem: fragment-parallel raised occupancy 40->78% and REGRESSED
// (88->113us), tracking its +16% line-requests. => throughput-bound at
// ~5.3 cyc/line-request/CU, not latency-bound.
// R7 theory: the ~5cyc/line is the L1 line-FILL path -- every random 16-B
// gather allocates a 128-B L1 line with zero reuse (1.07 GB of pure-waste
// fill traffic). nt loads skip L1 allocation; data still hits in per-XCD L2
// (table written there by phase 1, 1.6 MB << 4 MB).
// (R8 = R7 resubmitted verbatim; R7 bench was a GPUAcquisitionTimeout,
//  no measurement happened.)

typedef float        f4 __attribute__((ext_vector_type(4)));
typedef int          i4 __attribute__((ext_vector_type(4)));
typedef unsigned int u32;
typedef u32          u4 __attribute__((ext_vector_type(4)));

#define KFRAG 8
#define SIGMA_INV 10000.0f     // 1/1e-4
#define GAMMA_INV 10000.0f     // 1/1e-4
#define ZFAR 100.0f
#define ZRANGE_INV (1.0f / 99.0f)
#define EPSV 1e-10f
#define QSCALE 1023.0f
#define QINV (1.0f / 1023.0f)

__device__ __forceinline__ u32 pack10(float x, float y, float z) {
    // map [-1,1] -> [0,1023] unorm code; code/1023 == (n+1)/2
    u32 qx = (u32)__float2int_rn(__saturatef(x * 0.5f + 0.5f) * QSCALE);
    u32 qy = (u32)__float2int_rn(__saturatef(y * 0.5f + 0.5f) * QSCALE);
    u32 qz = (u32)__float2int_rn(__saturatef(z * 0.5f + 0.5f) * QSCALE);
    return qx | (qy << 10) | (qz << 20);
}

__global__ __launch_bounds__(256) void build_face_tab(
    const float* __restrict__ vn,     // [V,3]
    const int*   __restrict__ faces,  // [F,3]
    u4*          __restrict__ tab,    // [F] 16-B rows
    int F)
{
    int f = blockIdx.x * blockDim.x + threadIdx.x;
    if (f >= F) return;
    int v0 = faces[3*f + 0];
    int v1 = faces[3*f + 1];
    int v2 = faces[3*f + 2];
    u4 row;
    row.x = pack10(vn[3*v0], vn[3*v0+1], vn[3*v0+2]);
    row.y = pack10(vn[3*v1], vn[3*v1+1], vn[3*v1+2]);
    row.z = pack10(vn[3*v2], vn[3*v2+1], vn[3*v2+2]);
    row.w = 0;
    tab[f] = row;
}

__global__ __launch_bounds__(256) void soft_phong_kernel(
    const u4*    __restrict__ tab,    // [F] packed face rows
    const float* __restrict__ bary,   // [P,K,3]
    const float* __restrict__ zbuf,   // [P,K]
    const float* __restrict__ dists,  // [P,K]
    const int*   __restrict__ p2f,    // [P,K]
    float*       __restrict__ out,    // [P,4]
    int P)
{
    int p = blockIdx.x * blockDim.x + threadIdx.x;
    if (p >= P) return;

    // ---- streaming loads (contiguous; L2/L3-resident across replays) ----
    const i4* pf4 = (const i4*)(p2f + (size_t)p * KFRAG);
    i4 fa = pf4[0], fb = pf4[1];
    int fk[KFRAG] = {fa.x, fa.y, fa.z, fa.w, fb.x, fb.y, fb.z, fb.w};

    const f4* z4 = (const f4*)(zbuf + (size_t)p * KFRAG);
    f4 za = z4[0], zb = z4[1];
    float zk[KFRAG] = {za.x, za.y, za.z, za.w, zb.x, zb.y, zb.z, zb.w};

    const f4* dd4 = (const f4*)(dists + (size_t)p * KFRAG);
    f4 da = dd4[0], db = dd4[1];
    float dk[KFRAG] = {da.x, da.y, da.z, da.w, db.x, db.y, db.z, db.w};

    const f4* b4 = (const f4*)(bary + (size_t)p * KFRAG * 3);
    float bf[24];
    #pragma unroll
    for (int j = 0; j < 6; j++) {
        f4 t = b4[j];
        bf[4*j+0] = t.x; bf[4*j+1] = t.y; bf[4*j+2] = t.z; bf[4*j+3] = t.w;
    }

    // ---- face-table gathers: ONE 16-B nt load per fragment (no L1 alloc) ----
    u4 ga[KFRAG];
    #pragma unroll
    for (int k = 0; k < KFRAG; k++) {
        int fi = fk[k] >= 0 ? fk[k] : 0;
        ga[k] = __builtin_nontemporal_load(&tab[fi]);
    }

    // ---- per-fragment shading + blend precompute ----
    float prob[KFRAG], zinv[KFRAG];
    float cr[KFRAG], cg[KFRAG], cb[KFRAG];
    float zmax = EPSV;

    #pragma unroll
    for (int k = 0; k < KFRAG; k++) {
        bool m = (fk[k] >= 0);
        float b0 = bf[3*k + 0], b1 = bf[3*k + 1], b2 = bf[3*k + 2];

        u32 w0 = ga[k].x, w1 = ga[k].y, w2 = ga[k].z;
        // code/1023 = (n+1)/2; since b0+b1+b2 = 1:
        //   cr = (nx+1)/2 = (Σ b q_x)/1023 ; cg,cb = 1 - (Σ b q_{y,z})/1023
        float sx = b0 * (float)(w0 & 1023u)
                 + b1 * (float)(w1 & 1023u)
                 + b2 * (float)(w2 & 1023u);
        float sy = b0 * (float)((w0 >> 10) & 1023u)
                 + b1 * (float)((w1 >> 10) & 1023u)
                 + b2 * (float)((w2 >> 10) & 1023u);
        float sz = b0 * (float)(w0 >> 20)
                 + b1 * (float)(w1 >> 20)
                 + b2 * (float)(w2 >> 20);
        cr[k] = sx * QINV;
        cg[k] = 1.0f - sy * QINV;
        cb[k] = 1.0f - sz * QINV;

        prob[k] = m ? (1.0f / (1.0f + __expf(dk[k] * SIGMA_INV))) : 0.0f;
        zinv[k] = m ? ((ZFAR - zk[k]) * ZRANGE_INV) : 0.0f;
        zmax = fmaxf(zmax, zinv[k]);
    }

    // ---- softmax blend ----
    float delta = fmaxf(__expf((EPSV - zmax) * GAMMA_INV), EPSV);
    float denom = delta;
    float wr = 0.0f, wg = 0.0f, wb = 0.0f;
    float trans = 1.0f;

    #pragma unroll
    for (int k = 0; k < KFRAG; k++) {
        float w = prob[k] * __expf((zinv[k] - zmax) * GAMMA_INV);
        denom += w;
        wr += w * cr[k];
        wg += w * cg[k];
        wb += w * cb[k];
        trans *= (1.0f - prob[k]);
    }

    float inv = 1.0f / denom;
    f4 o = {(wr + delta) * inv, (wg + delta) * inv, (wb + delta) * inv, trans};
    __builtin_nontemporal_store(o, (f4*)out + p);   // write-once, keep out of caches
}

extern "C" void kernel_launch(void* const* d_in, const int* in_sizes, int n_in,
                              void* d_out, int out_size, void* d_ws, size_t ws_size,
                              hipStream_t stream) {
    const float* vn    = (const float*)d_in[0];  // verts_normals [V,3]
    const float* bary  = (const float*)d_in[1];  // [N,H,W,K,3]
    const float* zbuf  = (const float*)d_in[2];  // [N,H,W,K]
    const float* dists = (const float*)d_in[3];  // [N,H,W,K]
    const int*   faces = (const int*)d_in[4];    // [F,3]
    const int*   p2f   = (const int*)d_in[5];    // [N,H,W,K]
    float* out = (float*)d_out;                  // [N,H,W,4]

    int P = in_sizes[2] / KFRAG;   // N*H*W
    int F = in_sizes[4] / 3;

    u4* tab = (u4*)d_ws;           // F * 16 B = 1.6 MB
    int block = 256;
    build_face_tab<<<(F + block - 1) / block, block, 0, stream>>>(
        vn, faces, tab, F);
    soft_phong_kernel<<<(P + block - 1) / block, block, 0, stream>>>(
        tab, bary, zbuf, dists, p2f, out, P);
}

// Round 4
// 240.868 us; speedup vs baseline: 1.3664x; 1.3664x over previous
//
#include <hip/hip_runtime.h>

// SoftPhongNormalShader, two-phase (R9 = R4 structure + sc0 L1-bypass gathers):
//   Phase 1: per-face table, ONE 16-B row per face (3x10-bit unorm normals
//            per dword). 1.6 MB -> L2-resident.
//   Phase 2: per-pixel shade + softmax blend. Gathers use sc0 (GLC) loads:
//            bypass L1 allocation, read from L2, L2 caches normally.
//
// History: R4 88us baseline (pixel-parallel). R6 frag-parallel 113us
// (occupancy 78% but MLP/thread 8->1 => latency*MLP wall, not occupancy).
// R7/R8 nt gathers 177us, FETCH 105->350MB: nt poisons L2 retention, gathers
// fell to L3/HBM. Model: time ~ miss_lines * L_eff / N_slots, N~37/CU.
// R9 discriminates: if the ~5cyc/miss is the L1 128-B line-FILL port, sc0
// (no L1 alloc, L2 stays warm) wins 25-30%; if it's L2 random-request
// throughput or the miss-queue itself, null -> roofline.

typedef float        f4 __attribute__((ext_vector_type(4)));
typedef int          i4 __attribute__((ext_vector_type(4)));
typedef unsigned int u32;
typedef u32          u4 __attribute__((ext_vector_type(4)));

#define KFRAG 8
#define SIGMA_INV 10000.0f     // 1/1e-4
#define GAMMA_INV 10000.0f     // 1/1e-4
#define ZFAR 100.0f
#define ZRANGE_INV (1.0f / 99.0f)
#define EPSV 1e-10f
#define QSCALE 1023.0f
#define QINV (1.0f / 1023.0f)

__device__ __forceinline__ u32 pack10(float x, float y, float z) {
    // map [-1,1] -> [0,1023] unorm code; code/1023 == (n+1)/2
    u32 qx = (u32)__float2int_rn(__saturatef(x * 0.5f + 0.5f) * QSCALE);
    u32 qy = (u32)__float2int_rn(__saturatef(y * 0.5f + 0.5f) * QSCALE);
    u32 qz = (u32)__float2int_rn(__saturatef(z * 0.5f + 0.5f) * QSCALE);
    return qx | (qy << 10) | (qz << 20);
}

__global__ __launch_bounds__(256) void build_face_tab(
    const float* __restrict__ vn,     // [V,3]
    const int*   __restrict__ faces,  // [F,3]
    u4*          __restrict__ tab,    // [F] 16-B rows
    int F)
{
    int f = blockIdx.x * blockDim.x + threadIdx.x;
    if (f >= F) return;
    int v0 = faces[3*f + 0];
    int v1 = faces[3*f + 1];
    int v2 = faces[3*f + 2];
    u4 row;
    row.x = pack10(vn[3*v0], vn[3*v0+1], vn[3*v0+2]);
    row.y = pack10(vn[3*v1], vn[3*v1+1], vn[3*v1+2]);
    row.z = pack10(vn[3*v2], vn[3*v2+1], vn[3*v2+2]);
    row.w = 0;
    tab[f] = row;
}

__global__ __launch_bounds__(256) void soft_phong_kernel(
    const u4*    __restrict__ tab,    // [F] packed face rows
    const float* __restrict__ bary,   // [P,K,3]
    const float* __restrict__ zbuf,   // [P,K]
    const float* __restrict__ dists,  // [P,K]
    const int*   __restrict__ p2f,    // [P,K]
    float*       __restrict__ out,    // [P,4]
    int P)
{
    int p = blockIdx.x * blockDim.x + threadIdx.x;
    if (p >= P) return;

    // ---- streaming loads (contiguous; issued before the gather block so
    //      they overlap the gathers' vmcnt(0) drain) ----
    const i4* pf4 = (const i4*)(p2f + (size_t)p * KFRAG);
    i4 fa = pf4[0], fb = pf4[1];
    int fk[KFRAG] = {fa.x, fa.y, fa.z, fa.w, fb.x, fb.y, fb.z, fb.w};

    const f4* z4 = (const f4*)(zbuf + (size_t)p * KFRAG);
    f4 za = z4[0], zb = z4[1];
    float zk[KFRAG] = {za.x, za.y, za.z, za.w, zb.x, zb.y, zb.z, zb.w};

    const f4* dd4 = (const f4*)(dists + (size_t)p * KFRAG);
    f4 da = dd4[0], db = dd4[1];
    float dk[KFRAG] = {da.x, da.y, da.z, da.w, db.x, db.y, db.z, db.w};

    const f4* b4 = (const f4*)(bary + (size_t)p * KFRAG * 3);
    float bf[24];
    #pragma unroll
    for (int j = 0; j < 6; j++) {
        f4 t = b4[j];
        bf[4*j+0] = t.x; bf[4*j+1] = t.y; bf[4*j+2] = t.z; bf[4*j+3] = t.w;
    }

    // ---- face-table gathers: 8x 16-B sc0 loads (L1-bypass, L2-cached) ----
    // One asm block: all 8 stay outstanding, then one vmcnt(0). Load+wait in
    // the SAME block so dataflow (not a separate waitcnt) orders consumers.
    const u4* ap[KFRAG];
    #pragma unroll
    for (int k = 0; k < KFRAG; k++)
        ap[k] = tab + (fk[k] >= 0 ? fk[k] : 0);

    u4 g0, g1, g2, g3, g4, g5, g6, g7;
    asm volatile(
        "global_load_dwordx4 %0, %8,  off sc0\n\t"
        "global_load_dwordx4 %1, %9,  off sc0\n\t"
        "global_load_dwordx4 %2, %10, off sc0\n\t"
        "global_load_dwordx4 %3, %11, off sc0\n\t"
        "global_load_dwordx4 %4, %12, off sc0\n\t"
        "global_load_dwordx4 %5, %13, off sc0\n\t"
        "global_load_dwordx4 %6, %14, off sc0\n\t"
        "global_load_dwordx4 %7, %15, off sc0\n\t"
        "s_waitcnt vmcnt(0)"
        : "=&v"(g0), "=&v"(g1), "=&v"(g2), "=&v"(g3),
          "=&v"(g4), "=&v"(g5), "=&v"(g6), "=&v"(g7)
        : "v"(ap[0]), "v"(ap[1]), "v"(ap[2]), "v"(ap[3]),
          "v"(ap[4]), "v"(ap[5]), "v"(ap[6]), "v"(ap[7])
        : "memory");
    u4 ga[KFRAG] = {g0, g1, g2, g3, g4, g5, g6, g7};

    // ---- per-fragment shading + blend precompute ----
    float prob[KFRAG], zinv[KFRAG];
    float cr[KFRAG], cg[KFRAG], cb[KFRAG];
    float zmax = EPSV;

    #pragma unroll
    for (int k = 0; k < KFRAG; k++) {
        bool m = (fk[k] >= 0);
        float b0 = bf[3*k + 0], b1 = bf[3*k + 1], b2 = bf[3*k + 2];

        u32 w0 = ga[k].x, w1 = ga[k].y, w2 = ga[k].z;
        // code/1023 = (n+1)/2; since b0+b1+b2 = 1:
        //   cr = (nx+1)/2 = (Σ b q_x)/1023 ; cg,cb = 1 - (Σ b q_{y,z})/1023
        float sx = b0 * (float)(w0 & 1023u)
                 + b1 * (float)(w1 & 1023u)
                 + b2 * (float)(w2 & 1023u);
        float sy = b0 * (float)((w0 >> 10) & 1023u)
                 + b1 * (float)((w1 >> 10) & 1023u)
                 + b2 * (float)((w2 >> 10) & 1023u);
        float sz = b0 * (float)(w0 >> 20)
                 + b1 * (float)(w1 >> 20)
                 + b2 * (float)(w2 >> 20);
        cr[k] = sx * QINV;
        cg[k] = 1.0f - sy * QINV;
        cb[k] = 1.0f - sz * QINV;

        prob[k] = m ? (1.0f / (1.0f + __expf(dk[k] * SIGMA_INV))) : 0.0f;
        zinv[k] = m ? ((ZFAR - zk[k]) * ZRANGE_INV) : 0.0f;
        zmax = fmaxf(zmax, zinv[k]);
    }

    // ---- softmax blend ----
    float delta = fmaxf(__expf((EPSV - zmax) * GAMMA_INV), EPSV);
    float denom = delta;
    float wr = 0.0f, wg = 0.0f, wb = 0.0f;
    float trans = 1.0f;

    #pragma unroll
    for (int k = 0; k < KFRAG; k++) {
        float w = prob[k] * __expf((zinv[k] - zmax) * GAMMA_INV);
        denom += w;
        wr += w * cr[k];
        wg += w * cg[k];
        wb += w * cb[k];
        trans *= (1.0f - prob[k]);
    }

    float inv = 1.0f / denom;
    f4 o = {(wr + delta) * inv, (wg + delta) * inv, (wb + delta) * inv, trans};
    __builtin_nontemporal_store(o, (f4*)out + p);   // write-once, keep out of caches
}

extern "C" void kernel_launch(void* const* d_in, const int* in_sizes, int n_in,
                              void* d_out, int out_size, void* d_ws, size_t ws_size,
                              hipStream_t stream) {
    const float* vn    = (const float*)d_in[0];  // verts_normals [V,3]
    const float* bary  = (const float*)d_in[1];  // [N,H,W,K,3]
    const float* zbuf  = (const float*)d_in[2];  // [N,H,W,K]
    const float* dists = (const float*)d_in[3];  // [N,H,W,K]
    const int*   faces = (const int*)d_in[4];    // [F,3]
    const int*   p2f   = (const int*)d_in[5];    // [N,H,W,K]
    float* out = (float*)d_out;                  // [N,H,W,4]

    int P = in_sizes[2] / KFRAG;   // N*H*W
    int F = in_sizes[4] / 3;

    u4* tab = (u4*)d_ws;           // F * 16 B = 1.6 MB
    int block = 256;
    build_face_tab<<<(F + block - 1) / block, block, 0, stream>>>(
        vn, faces, tab, F);
    soft_phong_kernel<<<(P + block - 1) / block, block, 0, stream>>>(
        tab, bary, zbuf, dists, p2f, out, P);
}

// Round 5
// 233.260 us; speedup vs baseline: 1.4109x; 1.0326x over previous
//
#include <hip/hip_runtime.h>

// SoftPhongNormalShader, two-phase (R10 = R4 structure + SPARSE gathers):
//   Phase 1: per-face table, ONE 16-B row per face (3x10-bit unorm normals
//            per dword). 1.6 MB -> L2-resident.
//   Phase 2: per-pixel shade + softmax blend, but gather face normals ONLY
//            for fragments within THETA of the pixel's z_inv max.
//
// Why: gamma = 1e-4 makes the softmax blend a near-argmax. A fragment
// 0.0025 below z_max carries exp(-25) ~ 1.4e-11 relative color weight
// (prob only modulates by O(e^3)); dropping its COLOR is invisible at
// absmax 3.9e-3. denom/alpha/trans stay exact (streaming data only).
// Expected gathers/pixel: 1 + 7*THETA ~ 1.02 instead of 8.
//
// Wall model (R4..R9 evidence): time ~ line_requests * L_L2(200cy) / N(~44
// outstanding/CU). R6: +occupancy null. R7/R8: nt poisoned L2 -> latency
// tripled, time doubled. R9: L1-bypass (sc0) only -3.5% -> fill not wall.
// Only reducible term is LINE-REQUEST COUNT -> this kernel cuts it 3.5x.

typedef float        f4 __attribute__((ext_vector_type(4)));
typedef int          i4 __attribute__((ext_vector_type(4)));
typedef unsigned int u32;
typedef u32          u4 __attribute__((ext_vector_type(4)));

#define KFRAG 8
#define SIGMA_INV 10000.0f     // 1/1e-4
#define GAMMA_INV 10000.0f     // 1/1e-4
#define ZFAR 100.0f
#define ZRANGE_INV (1.0f / 99.0f)
#define EPSV 1e-10f
#define QSCALE 1023.0f
#define QINV (1.0f / 1023.0f)
#define THETA 0.0025f          // color-gather cutoff: exp(-25) rel weight

__device__ __forceinline__ u32 pack10(float x, float y, float z) {
    // map [-1,1] -> [0,1023] unorm code; code/1023 == (n+1)/2
    u32 qx = (u32)__float2int_rn(__saturatef(x * 0.5f + 0.5f) * QSCALE);
    u32 qy = (u32)__float2int_rn(__saturatef(y * 0.5f + 0.5f) * QSCALE);
    u32 qz = (u32)__float2int_rn(__saturatef(z * 0.5f + 0.5f) * QSCALE);
    return qx | (qy << 10) | (qz << 20);
}

__global__ __launch_bounds__(256) void build_face_tab(
    const float* __restrict__ vn,     // [V,3]
    const int*   __restrict__ faces,  // [F,3]
    u4*          __restrict__ tab,    // [F] 16-B rows
    int F)
{
    int f = blockIdx.x * blockDim.x + threadIdx.x;
    if (f >= F) return;
    int v0 = faces[3*f + 0];
    int v1 = faces[3*f + 1];
    int v2 = faces[3*f + 2];
    u4 row;
    row.x = pack10(vn[3*v0], vn[3*v0+1], vn[3*v0+2]);
    row.y = pack10(vn[3*v1], vn[3*v1+1], vn[3*v1+2]);
    row.z = pack10(vn[3*v2], vn[3*v2+1], vn[3*v2+2]);
    row.w = 0;
    tab[f] = row;
}

__global__ __launch_bounds__(256) void soft_phong_kernel(
    const u4*    __restrict__ tab,    // [F] packed face rows
    const float* __restrict__ bary,   // [P,K,3]
    const float* __restrict__ zbuf,   // [P,K]
    const float* __restrict__ dists,  // [P,K]
    const int*   __restrict__ p2f,    // [P,K]
    float*       __restrict__ out,    // [P,4]
    int P)
{
    int p = blockIdx.x * blockDim.x + threadIdx.x;
    if (p >= P) return;

    // ---- streaming loads (contiguous, coalesced 16-B) ----
    const i4* pf4 = (const i4*)(p2f + (size_t)p * KFRAG);
    i4 fa = pf4[0], fb = pf4[1];
    int fk[KFRAG] = {fa.x, fa.y, fa.z, fa.w, fb.x, fb.y, fb.z, fb.w};

    const f4* z4 = (const f4*)(zbuf + (size_t)p * KFRAG);
    f4 za = z4[0], zb = z4[1];
    float zk[KFRAG] = {za.x, za.y, za.z, za.w, zb.x, zb.y, zb.z, zb.w};

    const f4* dd4 = (const f4*)(dists + (size_t)p * KFRAG);
    f4 da = dd4[0], db = dd4[1];
    float dk[KFRAG] = {da.x, da.y, da.z, da.w, db.x, db.y, db.z, db.w};

    const f4* b4 = (const f4*)(bary + (size_t)p * KFRAG * 3);
    float bf[24];
    #pragma unroll
    for (int j = 0; j < 6; j++) {
        f4 t = b4[j];
        bf[4*j+0] = t.x; bf[4*j+1] = t.y; bf[4*j+2] = t.z; bf[4*j+3] = t.w;
    }

    // ---- per-fragment prob / z_inv; pixel z_max (streaming only) ----
    float prob[KFRAG], zinv[KFRAG];
    float zmax = EPSV;
    #pragma unroll
    for (int k = 0; k < KFRAG; k++) {
        bool m = (fk[k] >= 0);
        prob[k] = m ? (1.0f / (1.0f + __expf(dk[k] * SIGMA_INV))) : 0.0f;
        zinv[k] = m ? ((ZFAR - zk[k]) * ZRANGE_INV) : 0.0f;
        zmax = fmaxf(zmax, zinv[k]);
    }

    // ---- exact blend weights / denom / transparency (no gathers) ----
    float delta = fmaxf(__expf((EPSV - zmax) * GAMMA_INV), EPSV);
    float denom = delta;
    float trans = 1.0f;
    float wgt[KFRAG];
    #pragma unroll
    for (int k = 0; k < KFRAG; k++) {
        wgt[k] = prob[k] * __expf((zinv[k] - zmax) * GAMMA_INV);
        denom += wgt[k];
        trans *= (1.0f - prob[k]);
    }

    // ---- SPARSE color gathers: only fragments near z_max matter ----
    float wr = 0.0f, wg = 0.0f, wb = 0.0f;
    #pragma unroll
    for (int k = 0; k < KFRAG; k++) {
        if (zmax - zinv[k] < THETA) {          // ~12.7% of lanes per k
            int fi = fk[k] >= 0 ? fk[k] : 0;
            u4 row = tab[fi];                  // divergent 16-B, exec-masked
            u32 w0 = row.x, w1 = row.y, w2 = row.z;
            float b0 = bf[3*k + 0], b1 = bf[3*k + 1], b2 = bf[3*k + 2];
            // code/1023 = (n+1)/2; b0+b1+b2 = 1:
            float sx = b0 * (float)(w0 & 1023u)
                     + b1 * (float)(w1 & 1023u)
                     + b2 * (float)(w2 & 1023u);
            float sy = b0 * (float)((w0 >> 10) & 1023u)
                     + b1 * (float)((w1 >> 10) & 1023u)
                     + b2 * (float)((w2 >> 10) & 1023u);
            float sz = b0 * (float)(w0 >> 20)
                     + b1 * (float)(w1 >> 20)
                     + b2 * (float)(w2 >> 20);
            float cr = sx * QINV;
            float cg = 1.0f - sy * QINV;
            float cb = 1.0f - sz * QINV;
            wr += wgt[k] * cr;
            wg += wgt[k] * cg;
            wb += wgt[k] * cb;
        }
    }

    float inv = 1.0f / denom;
    f4 o = {(wr + delta) * inv, (wg + delta) * inv, (wb + delta) * inv, trans};
    __builtin_nontemporal_store(o, (f4*)out + p);   // write-once
}

extern "C" void kernel_launch(void* const* d_in, const int* in_sizes, int n_in,
                              void* d_out, int out_size, void* d_ws, size_t ws_size,
                              hipStream_t stream) {
    const float* vn    = (const float*)d_in[0];  // verts_normals [V,3]
    const float* bary  = (const float*)d_in[1];  // [N,H,W,K,3]
    const float* zbuf  = (const float*)d_in[2];  // [N,H,W,K]
    const float* dists = (const float*)d_in[3];  // [N,H,W,K]
    const int*   faces = (const int*)d_in[4];    // [F,3]
    const int*   p2f   = (const int*)d_in[5];    // [N,H,W,K]
    float* out = (float*)d_out;                  // [N,H,W,4]

    int P = in_sizes[2] / KFRAG;   // N*H*W
    int F = in_sizes[4] / 3;

    u4* tab = (u4*)d_ws;           // F * 16 B = 1.6 MB
    int block = 256;
    build_face_tab<<<(F + block - 1) / block, block, 0, stream>>>(
        vn, faces, tab, F);
    soft_phong_kernel<<<(P + block - 1) / block, block, 0, stream>>>(
        tab, bary, zbuf, dists, p2f, out, P);
}